// Round 5
// baseline (250.946 us; speedup 1.0000x reference)
//
#include <hip/hip_runtime.h>

// Problem constants (from reference setup_inputs)
constexpr int Bb = 32;      // batch
constexpr int Mm = 65536;   // memory slots
constexpr int Ww = 32;      // word width
constexpr int Rr = 4;       // read heads
constexpr int Dd = 256;     // d_in
constexpr int Kk = 8;       // K_NEIGHBORS

constexpr int NB_A = 32;                    // blocks per batch, phase A
constexpr int TPB_A = 256;                  // threads per block
constexpr int ROWS_PER_BLOCK = Mm / NB_A;   // 2048
constexpr int TILE_ROWS = 256;              // rows per LDS tile (= TPB_A)
constexpr int TILES = ROWS_PER_BLOCK / TILE_ROWS;  // 8
constexpr int CPL = NB_A * Kk / 64;         // final-merge candidates per lane = 4

// async global->LDS, 16 B per lane; LDS dest = uniform base + lane*16
__device__ __forceinline__ void glds16(const float4* src, float4* dst_lds) {
  __builtin_amdgcn_global_load_lds(
      (const __attribute__((address_space(1))) void*)src,
      (__attribute__((address_space(3))) void*)dst_lds, 16, 0, 0);
}

// ---------------------------------------------------------------------------
// Kernel 1: read_keys = xi @ W_rk^T + b_rk  (32 x 128), plus ||rk||^2 per (b,r)
// ---------------------------------------------------------------------------
__global__ __launch_bounds__(128) void rk_kernel(
    const float* __restrict__ xi, const float* __restrict__ Wrk,
    const float* __restrict__ brk, float* __restrict__ rk,
    float* __restrict__ rknorm) {
  const int b = blockIdx.x;
  const int tid = threadIdx.x;  // 128 threads = one rw each
  __shared__ float xs[Dd];
  __shared__ float rks[Rr * Ww];
  #pragma unroll
  for (int i = 0; i < Dd; i += 128) xs[i + tid] = xi[b * Dd + i + tid];
  __syncthreads();
  float acc = brk[tid];
  const float4* wr = reinterpret_cast<const float4*>(Wrk + (size_t)tid * Dd);
  #pragma unroll 4
  for (int i = 0; i < Dd / 4; ++i) {
    float4 wv = wr[i];
    acc = fmaf(wv.x, xs[4 * i + 0], acc);
    acc = fmaf(wv.y, xs[4 * i + 1], acc);
    acc = fmaf(wv.z, xs[4 * i + 2], acc);
    acc = fmaf(wv.w, xs[4 * i + 3], acc);
  }
  rk[b * Rr * Ww + tid] = acc;
  rks[tid] = acc;
  __syncthreads();
  if (tid < Rr) {
    float s = 0.f;
    #pragma unroll
    for (int j = 0; j < Ww; ++j) s = fmaf(rks[tid * Ww + j], rks[tid * Ww + j], s);
    rknorm[b * Rr + tid] = s;
  }
}

// ---------------------------------------------------------------------------
// Kernel 2: double-buffered global_load_lds pipeline, counted vmcnt, NO
// barriers in the main loop (each wave reads only rows it staged itself).
// Chunk XOR-swizzle applied as pre-swizzled GLOBAL source + swizzled LDS
// READ (gload_lds dest must stay linear). Thread-per-row d2; per-thread
// candidate slot t = tile index (row = rowBlk + tid + t*256, recomputed,
// fully static indexing -> no spill, no cross-lane in the hot loop).
// ---------------------------------------------------------------------------
__global__ __launch_bounds__(TPB_A, 2) void topk_partial(
    const float* __restrict__ sparse, const float* __restrict__ rk,
    const float* __restrict__ rknorm, float* __restrict__ cand_d,
    int* __restrict__ cand_i) {
  const int b = blockIdx.y;
  const int tid = threadIdx.x;
  const int lane = tid & 63;
  const int wid = tid >> 6;
  const float INF = __builtin_inff();

  __shared__ float rk_s[Rr][Ww];
  __shared__ float rkn_s[Rr];
  __shared__ float4 tile[2][TILE_ROWS * 8];   // 2 x 32 KB
  __shared__ float swv[4][Rr][Kk];
  __shared__ int swi[4][Rr][Kk];

  if (tid < Rr * Ww) rk_s[tid >> 5][tid & 31] = rk[b * Rr * Ww + tid];
  if (tid < Rr) rkn_s[tid] = rknorm[b * Rr + tid];
  __syncthreads();

  // full read_keys in registers (128 VGPR; LDS caps occupancy anyway)
  float4 rkr[Rr][8];
  float rkn[Rr];
  #pragma unroll
  for (int r = 0; r < Rr; ++r) {
    #pragma unroll
    for (int j = 0; j < 8; ++j)
      rkr[r][j] = *reinterpret_cast<const float4*>(&rk_s[r][4 * j]);
    rkn[r] = rkn_s[r];
  }

  const int rowBlk = blockIdx.x * ROWS_PER_BLOCK;
  const float4* sb4 =
      reinterpret_cast<const float4*>(sparse) + (size_t)b * Mm * 8;
  // per-lane permuted source chunk within each 8-row (1 KB) group:
  // LDS slot (row, s) receives global chunk s ^ (row&7)
  const int perm = ((lane >> 3) * 8) + ((lane & 7) ^ (lane >> 3));

  float d8[Rr][TILES];
  #pragma unroll
  for (int r = 0; r < Rr; ++r)
    #pragma unroll
    for (int t = 0; t < TILES; ++t) d8[r][t] = INF;

  // wave wid stages rows [wid*64, wid*64+64) of tile t: 8 x 1 KB gload_lds
  auto STAGE = [&](int buf, int t) {
    const float4* g0 = sb4 + (size_t)(rowBlk + t * TILE_ROWS + wid * 64) * 8;
    float4* l0 = &tile[buf][wid * 64 * 8];
    #pragma unroll
    for (int i = 0; i < 8; ++i) glds16(g0 + i * 64 + perm, l0 + i * 64);
  };

  STAGE(0, 0);
  #pragma unroll
  for (int t = 0; t < TILES; ++t) {
    if (t + 1 < TILES) {
      // prior ds_reads complete before overwriting the other buffer (WAR)
      asm volatile("s_waitcnt lgkmcnt(0)" ::: "memory");
      STAGE((t + 1) & 1, t + 1);
      asm volatile("s_waitcnt vmcnt(8)" ::: "memory");  // tile t landed
    } else {
      asm volatile("s_waitcnt vmcnt(0)" ::: "memory");
    }
    // compute: thread's row = tid of tile t (staged by its own wave)
    const float4* rowp = &tile[t & 1][tid * 8];
    float dot[Rr] = {0.f, 0.f, 0.f, 0.f};
    float ss = 0.f;
    #pragma unroll
    for (int j = 0; j < 8; ++j) {
      float4 v = rowp[j ^ (tid & 7)];
      #pragma unroll
      for (int r = 0; r < Rr; ++r) {
        dot[r] = fmaf(rkr[r][j].x, v.x, dot[r]);
        dot[r] = fmaf(rkr[r][j].y, v.y, dot[r]);
        dot[r] = fmaf(rkr[r][j].z, v.z, dot[r]);
        dot[r] = fmaf(rkr[r][j].w, v.w, dot[r]);
      }
      ss = fmaf(v.x, v.x, ss);
      ss = fmaf(v.y, v.y, ss);
      ss = fmaf(v.z, v.z, ss);
      ss = fmaf(v.w, v.w, ss);
    }
    #pragma unroll
    for (int r = 0; r < Rr; ++r)
      d8[r][t] = fmaf(-2.f, dot[r], rkn[r] + ss);
  }

  // --- wave-local top-8 per r: 8 rounds of {static slot argmin ->
  //     butterfly -> static per-slot clear}; no dynamic indexing ---
  const int base = rowBlk + tid;  // slot t holds row base + t*256
  #pragma unroll
  for (int r = 0; r < Rr; ++r) {
    #pragma unroll
    for (int k = 0; k < Kk; ++k) {
      float lv = d8[r][0];
      int lidx = base;
      #pragma unroll
      for (int t = 1; t < TILES; ++t)
        if (d8[r][t] < lv) { lv = d8[r][t]; lidx = base + t * TILE_ROWS; }
      float bv = lv;
      int bi = lidx;
      #pragma unroll
      for (int off = 32; off; off >>= 1) {
        float ov = __shfl_xor(bv, off);
        int oi = __shfl_xor(bi, off);
        if (ov < bv || (ov == bv && oi < bi)) { bv = ov; bi = oi; }
      }
      if (lane == 0) { swv[wid][r][k] = bv; swi[wid][r][k] = bi; }
      #pragma unroll
      for (int t = 0; t < TILES; ++t) {
        bool clr = (d8[r][t] == bv) && (base + t * TILE_ROWS == bi);
        d8[r][t] = clr ? INF : d8[r][t];
      }
    }
  }
  __syncthreads();

  // --- merge 4 waves x 8 -> block top-8; wave `wid` handles r = wid ---
  {
    const int r = wid;
    float v = INF;
    int id = 0x7fffffff;
    if (lane < 32) { v = swv[lane >> 3][r][lane & 7]; id = swi[lane >> 3][r][lane & 7]; }
    size_t o = ((size_t)(b * Rr + r) * NB_A + blockIdx.x) * Kk;
    #pragma unroll
    for (int k = 0; k < Kk; ++k) {
      float bv = v;
      int bi = id;
      #pragma unroll
      for (int off = 32; off; off >>= 1) {
        float ov = __shfl_xor(bv, off);
        int oi = __shfl_xor(bi, off);
        if (ov < bv || (ov == bv && oi < bi)) { bv = ov; bi = oi; }
      }
      if (lane == 0) { cand_d[o + k] = bv; cand_i[o + k] = bi; }
      if (v == bv && id == bi) { v = INF; id = 0x7fffffff; }  // pop self
    }
  }
}

// ---------------------------------------------------------------------------
// Kernel 3: merge 32*8 candidates per (b,r) -> global top-8, weights, gather
// ---------------------------------------------------------------------------
__global__ __launch_bounds__(64) void topk_final(
    const float* __restrict__ sparse, const float* __restrict__ cand_d,
    const int* __restrict__ cand_i, float* __restrict__ out) {
  const int br = blockIdx.x;  // b*4 + r
  const int b = br >> 2;
  const int r = br & 3;
  const int lane = threadIdx.x;  // 64
  const float INF = __builtin_inff();

  float ld[CPL];
  int li[CPL];
  const float* cd = cand_d + (size_t)br * (NB_A * Kk);
  const int* ci = cand_i + (size_t)br * (NB_A * Kk);
  #pragma unroll
  for (int t = 0; t < CPL; ++t) {
    ld[t] = cd[t * 64 + lane];
    li[t] = ci[t * 64 + lane];
  }
  // sort per-lane list ascending (static bubble network)
  #pragma unroll
  for (int i = 0; i < CPL - 1; ++i)
    #pragma unroll
    for (int j = 0; j < CPL - 1 - i; ++j)
      if (ld[j + 1] < ld[j] || (ld[j + 1] == ld[j] && li[j + 1] < li[j])) {
        float td = ld[j]; ld[j] = ld[j + 1]; ld[j + 1] = td;
        int ti = li[j]; li[j] = li[j + 1]; li[j + 1] = ti;
      }

  __shared__ float s_td[Kk];
  __shared__ int s_ti[Kk];
  #pragma unroll
  for (int k = 0; k < Kk; ++k) {
    float v = ld[0];
    int id = li[0];
    #pragma unroll
    for (int off = 32; off; off >>= 1) {  // butterfly: all lanes get the min
      float ov = __shfl_xor(v, off);
      int oi = __shfl_xor(id, off);
      if (ov < v || (ov == v && oi < id)) { v = ov; id = oi; }
    }
    if (lane == 0) { s_td[k] = v; s_ti[k] = id; }
    if (li[0] == id) {  // owner pops head
      #pragma unroll
      for (int j = 0; j < CPL - 1; ++j) { ld[j] = ld[j + 1]; li[j] = li[j + 1]; }
      ld[CPL - 1] = INF;
      li[CPL - 1] = -1;
    }
  }
  __syncthreads();

  // read_weights[r][b][k] = dist_k / dist_7  (dist ascending -> max is last)
  const float dmax = s_td[Kk - 1];
  if (lane < Kk)
    out[(size_t)Rr * Bb * Kk * Ww + ((size_t)r * Bb + b) * Kk + lane] =
        s_td[lane] / dmax;

  // read_vectors[r][b][k][j] = sparse[b][idx_k][j]
  const float* sbase = sparse + (size_t)b * Mm * Ww;
  #pragma unroll
  for (int t = 0; t < (Kk * Ww) / 64; ++t) {
    int e = t * 64 + lane;
    int k = e >> 5;
    int j = e & 31;
    out[(((size_t)r * Bb + b) * Kk + k) * Ww + j] =
        sbase[(size_t)s_ti[k] * Ww + j];
  }
}

// ---------------------------------------------------------------------------
extern "C" void kernel_launch(void* const* d_in, const int* in_sizes, int n_in,
                              void* d_out, int out_size, void* d_ws,
                              size_t ws_size, hipStream_t stream) {
  const float* xi = (const float*)d_in[0];
  const float* sparse = (const float*)d_in[1];
  const float* Wrk = (const float*)d_in[2];
  const float* brk = (const float*)d_in[3];
  float* out = (float*)d_out;

  char* ws = (char*)d_ws;
  float* rk = (float*)ws;                          // 32*128*4      = 16384 B
  float* rknorm = (float*)(ws + 16384);            // 128*4         = 512 B
  float* cand_d = (float*)(ws + 16896);            // 32*4*32*8*4   = 131072 B
  int* cand_i = (int*)(ws + 16896 + 131072);       // 131072 B

  rk_kernel<<<Bb, 128, 0, stream>>>(xi, Wrk, brk, rk, rknorm);
  dim3 gridA(NB_A, Bb);
  topk_partial<<<gridA, TPB_A, 0, stream>>>(sparse, rk, rknorm, cand_d, cand_i);
  topk_final<<<Bb * Rr, 64, 0, stream>>>(sparse, cand_d, cand_i, out);
}

// Round 6
// 135.597 us; speedup vs baseline: 1.8507x; 1.8507x over previous
//
#include <hip/hip_runtime.h>

// Problem constants (from reference setup_inputs)
constexpr int Bb = 32;      // batch
constexpr int Mm = 65536;   // memory slots
constexpr int Ww = 32;      // word width
constexpr int Rr = 4;       // read heads
constexpr int Dd = 256;     // d_in
constexpr int Kk = 8;       // K_NEIGHBORS

constexpr int NB_A = 64;                    // blocks per batch, phase A
constexpr int TPB_A = 256;                  // threads per block
constexpr int ROWS_PER_BLOCK = Mm / NB_A;   // 1024
constexpr int TILE_ROWS = 128;              // rows per LDS tile (2 thr/row)
constexpr int TILES = ROWS_PER_BLOCK / TILE_ROWS;  // 8
constexpr int CPL = NB_A * Kk / 64;         // final-merge candidates/lane = 8

// async global->LDS, 16 B per lane; LDS dest = uniform base + lane*16
__device__ __forceinline__ void glds16(const float4* src, float4* dst_lds) {
  __builtin_amdgcn_global_load_lds(
      (const __attribute__((address_space(1))) void*)src,
      (__attribute__((address_space(3))) void*)dst_lds, 16, 0, 0);
}

// ---------------------------------------------------------------------------
// Kernel 1: read_keys = xi @ W_rk^T + b_rk  (32 x 128), plus ||rk||^2 per (b,r)
// ---------------------------------------------------------------------------
__global__ __launch_bounds__(128) void rk_kernel(
    const float* __restrict__ xi, const float* __restrict__ Wrk,
    const float* __restrict__ brk, float* __restrict__ rk,
    float* __restrict__ rknorm) {
  const int b = blockIdx.x;
  const int tid = threadIdx.x;  // 128 threads = one rw each
  __shared__ float xs[Dd];
  __shared__ float rks[Rr * Ww];
  #pragma unroll
  for (int i = 0; i < Dd; i += 128) xs[i + tid] = xi[b * Dd + i + tid];
  __syncthreads();
  float acc = brk[tid];
  const float4* wr = reinterpret_cast<const float4*>(Wrk + (size_t)tid * Dd);
  #pragma unroll 4
  for (int i = 0; i < Dd / 4; ++i) {
    float4 wv = wr[i];
    acc = fmaf(wv.x, xs[4 * i + 0], acc);
    acc = fmaf(wv.y, xs[4 * i + 1], acc);
    acc = fmaf(wv.z, xs[4 * i + 2], acc);
    acc = fmaf(wv.w, xs[4 * i + 3], acc);
  }
  rk[b * Rr * Ww + tid] = acc;
  rks[tid] = acc;
  __syncthreads();
  if (tid < Rr) {
    float s = 0.f;
    #pragma unroll
    for (int j = 0; j < Ww; ++j) s = fmaf(rks[tid * Ww + j], rks[tid * Ww + j], s);
    rknorm[b * Rr + tid] = s;
  }
}

// ---------------------------------------------------------------------------
// Kernel 2: gload_lds double-buffered pipeline, counted vmcnt, no barriers
// in the main loop (wave-private staging/reads). 128-row tiles, 2 threads
// per row (16 floats each), one shfl_xor(,1) finishes each distance.
// Chunk XOR-swizzle: pre-swizzled GLOBAL source + swizzled LDS READ (the
// gload_lds LDS dest stays linear). rk fragments re-read from LDS per tile
// (2-addr ds_read_b128) so registers stay ~100 -> no spill.
// ---------------------------------------------------------------------------
__global__ __launch_bounds__(TPB_A, 4) void topk_partial(
    const float* __restrict__ sparse, const float* __restrict__ rk,
    const float* __restrict__ rknorm, float* __restrict__ cand_d,
    int* __restrict__ cand_i) {
  const int b = blockIdx.y;
  const int tid = threadIdx.x;
  const int lane = tid & 63;
  const int wid = tid >> 6;
  const float INF = __builtin_inff();

  __shared__ float4 rk4[Rr][8];               // 512 B (linear float view ok)
  __shared__ float rkn_s[Rr];
  __shared__ float4 tile[2][TILE_ROWS * 8];   // 2 x 16 KB
  __shared__ float swv[4][Rr][Kk];
  __shared__ int swi[4][Rr][Kk];

  if (tid < Rr * Ww) reinterpret_cast<float*>(rk4)[tid] = rk[b * Rr * Ww + tid];
  if (tid < Rr) rkn_s[tid] = rknorm[b * Rr + tid];
  __syncthreads();

  float rkn[Rr];
  #pragma unroll
  for (int r = 0; r < Rr; ++r) rkn[r] = rkn_s[r];

  const int rowBlk = blockIdx.x * ROWS_PER_BLOCK;
  const float4* sb4 =
      reinterpret_cast<const float4*>(sparse) + (size_t)b * Mm * 8;
  // staging source permutation: LDS slot (row, s) receives global chunk
  // s ^ (row&7); groups are 8-row aligned so row&7 == lane>>3 within a gload
  const int perm = ((lane >> 3) * 8) + ((lane & 7) ^ (lane >> 3));

  const int rowL = wid * 32 + (lane >> 1);  // local tile row (2 thr/row)
  const int rmask = rowL & 7;
  const int hsel = (tid & 1) * 4;           // this thread's 4 chunks

  float d8[Rr][TILES];
  #pragma unroll
  for (int r = 0; r < Rr; ++r)
    #pragma unroll
    for (int t = 0; t < TILES; ++t) d8[r][t] = INF;

  // wave wid stages rows [wid*32, wid*32+32) of a tile: 4 x 1 KB gload_lds
  auto STAGE = [&](int buf, int t) {
    const float4* g0 = sb4 + (size_t)(rowBlk + t * TILE_ROWS + wid * 32) * 8;
    float4* l0 = &tile[buf][wid * 32 * 8];
    #pragma unroll
    for (int i = 0; i < 4; ++i) glds16(g0 + i * 64 + perm, l0 + i * 64);
  };

  STAGE(0, 0);
  #pragma unroll
  for (int t = 0; t < TILES; ++t) {
    if (t + 1 < TILES) {
      // this wave's prior ds_reads done before overwriting other buf (WAR)
      asm volatile("s_waitcnt lgkmcnt(0)" ::: "memory");
      STAGE((t + 1) & 1, t + 1);
      asm volatile("s_waitcnt vmcnt(4)" ::: "memory");  // tile t landed
    } else {
      asm volatile("s_waitcnt vmcnt(0)" ::: "memory");
    }
    const float4* tb = &tile[t & 1][rowL * 8];
    float a0 = 0.f, a1 = 0.f, a2 = 0.f, a3 = 0.f, ss = 0.f;
    #pragma unroll
    for (int j = 0; j < 4; ++j) {
      float4 v = tb[(hsel + j) ^ rmask];
      float4 k0 = rk4[0][hsel + j];
      float4 k1 = rk4[1][hsel + j];
      float4 k2 = rk4[2][hsel + j];
      float4 k3 = rk4[3][hsel + j];
      a0 = fmaf(k0.x, v.x, a0); a0 = fmaf(k0.y, v.y, a0);
      a0 = fmaf(k0.z, v.z, a0); a0 = fmaf(k0.w, v.w, a0);
      a1 = fmaf(k1.x, v.x, a1); a1 = fmaf(k1.y, v.y, a1);
      a1 = fmaf(k1.z, v.z, a1); a1 = fmaf(k1.w, v.w, a1);
      a2 = fmaf(k2.x, v.x, a2); a2 = fmaf(k2.y, v.y, a2);
      a2 = fmaf(k2.z, v.z, a2); a2 = fmaf(k2.w, v.w, a2);
      a3 = fmaf(k3.x, v.x, a3); a3 = fmaf(k3.y, v.y, a3);
      a3 = fmaf(k3.z, v.z, a3); a3 = fmaf(k3.w, v.w, a3);
      ss = fmaf(v.x, v.x, ss); ss = fmaf(v.y, v.y, ss);
      ss = fmaf(v.z, v.z, ss); ss = fmaf(v.w, v.w, ss);
    }
    // partial d2 per head = ss - 2*dot over this half; partner adds the rest
    float p0 = fmaf(-2.f, a0, ss);
    float p1 = fmaf(-2.f, a1, ss);
    float p2 = fmaf(-2.f, a2, ss);
    float p3 = fmaf(-2.f, a3, ss);
    p0 += __shfl_xor(p0, 1);
    p1 += __shfl_xor(p1, 1);
    p2 += __shfl_xor(p2, 1);
    p3 += __shfl_xor(p3, 1);
    d8[0][t] = p0 + rkn[0];
    d8[1][t] = p1 + rkn[1];
    d8[2][t] = p2 + rkn[2];
    d8[3][t] = p3 + rkn[3];
  }

  // --- wave-local top-8 per r: 8 rounds of {static slot argmin ->
  //     butterfly -> static per-slot clear}. Partner lanes hold duplicate
  //     (val,idx) pairs; both clear on a win, so extraction stays distinct.
  const int base = rowBlk + rowL;  // slot t holds row base + t*128
  #pragma unroll
  for (int r = 0; r < Rr; ++r) {
    #pragma unroll
    for (int k = 0; k < Kk; ++k) {
      float lv = d8[r][0];
      int lidx = base;
      #pragma unroll
      for (int t = 1; t < TILES; ++t)
        if (d8[r][t] < lv) { lv = d8[r][t]; lidx = base + t * TILE_ROWS; }
      float bv = lv;
      int bi = lidx;
      #pragma unroll
      for (int off = 32; off; off >>= 1) {
        float ov = __shfl_xor(bv, off);
        int oi = __shfl_xor(bi, off);
        if (ov < bv || (ov == bv && oi < bi)) { bv = ov; bi = oi; }
      }
      if (lane == 0) { swv[wid][r][k] = bv; swi[wid][r][k] = bi; }
      #pragma unroll
      for (int t = 0; t < TILES; ++t) {
        bool clr = (d8[r][t] == bv) && (base + t * TILE_ROWS == bi);
        d8[r][t] = clr ? INF : d8[r][t];
      }
    }
  }
  __syncthreads();

  // --- merge 4 waves x 8 -> block top-8; wave `wid` handles r = wid ---
  {
    const int r = wid;
    float v = INF;
    int id = 0x7fffffff;
    if (lane < 32) { v = swv[lane >> 3][r][lane & 7]; id = swi[lane >> 3][r][lane & 7]; }
    size_t o = ((size_t)(b * Rr + r) * NB_A + blockIdx.x) * Kk;
    #pragma unroll
    for (int k = 0; k < Kk; ++k) {
      float bv = v;
      int bi = id;
      #pragma unroll
      for (int off = 32; off; off >>= 1) {
        float ov = __shfl_xor(bv, off);
        int oi = __shfl_xor(bi, off);
        if (ov < bv || (ov == bv && oi < bi)) { bv = ov; bi = oi; }
      }
      if (lane == 0) { cand_d[o + k] = bv; cand_i[o + k] = bi; }
      if (v == bv && id == bi) { v = INF; id = 0x7fffffff; }  // pop self
    }
  }
}

// ---------------------------------------------------------------------------
// Kernel 3: merge 64*8 candidates per (b,r) -> global top-8, weights, gather
// ---------------------------------------------------------------------------
__global__ __launch_bounds__(64) void topk_final(
    const float* __restrict__ sparse, const float* __restrict__ cand_d,
    const int* __restrict__ cand_i, float* __restrict__ out) {
  const int br = blockIdx.x;  // b*4 + r
  const int b = br >> 2;
  const int r = br & 3;
  const int lane = threadIdx.x;  // 64
  const float INF = __builtin_inff();

  float ld[CPL];
  int li[CPL];
  const float* cd = cand_d + (size_t)br * (NB_A * Kk);
  const int* ci = cand_i + (size_t)br * (NB_A * Kk);
  #pragma unroll
  for (int t = 0; t < CPL; ++t) {
    ld[t] = cd[t * 64 + lane];
    li[t] = ci[t * 64 + lane];
  }
  // sort per-lane list ascending (static bubble network)
  #pragma unroll
  for (int i = 0; i < CPL - 1; ++i)
    #pragma unroll
    for (int j = 0; j < CPL - 1 - i; ++j)
      if (ld[j + 1] < ld[j] || (ld[j + 1] == ld[j] && li[j + 1] < li[j])) {
        float td = ld[j]; ld[j] = ld[j + 1]; ld[j + 1] = td;
        int ti = li[j]; li[j] = li[j + 1]; li[j + 1] = ti;
      }

  __shared__ float s_td[Kk];
  __shared__ int s_ti[Kk];
  #pragma unroll
  for (int k = 0; k < Kk; ++k) {
    float v = ld[0];
    int id = li[0];
    #pragma unroll
    for (int off = 32; off; off >>= 1) {  // butterfly: all lanes get the min
      float ov = __shfl_xor(v, off);
      int oi = __shfl_xor(id, off);
      if (ov < v || (ov == v && oi < id)) { v = ov; id = oi; }
    }
    if (lane == 0) { s_td[k] = v; s_ti[k] = id; }
    if (li[0] == id) {  // owner pops head
      #pragma unroll
      for (int j = 0; j < CPL - 1; ++j) { ld[j] = ld[j + 1]; li[j] = li[j + 1]; }
      ld[CPL - 1] = INF;
      li[CPL - 1] = -1;
    }
  }
  __syncthreads();

  // read_weights[r][b][k] = dist_k / dist_7  (dist ascending -> max is last)
  const float dmax = s_td[Kk - 1];
  if (lane < Kk)
    out[(size_t)Rr * Bb * Kk * Ww + ((size_t)r * Bb + b) * Kk + lane] =
        s_td[lane] / dmax;

  // read_vectors[r][b][k][j] = sparse[b][idx_k][j]
  const float* sbase = sparse + (size_t)b * Mm * Ww;
  #pragma unroll
  for (int t = 0; t < (Kk * Ww) / 64; ++t) {
    int e = t * 64 + lane;
    int k = e >> 5;
    int j = e & 31;
    out[(((size_t)r * Bb + b) * Kk + k) * Ww + j] =
        sbase[(size_t)s_ti[k] * Ww + j];
  }
}

// ---------------------------------------------------------------------------
extern "C" void kernel_launch(void* const* d_in, const int* in_sizes, int n_in,
                              void* d_out, int out_size, void* d_ws,
                              size_t ws_size, hipStream_t stream) {
  const float* xi = (const float*)d_in[0];
  const float* sparse = (const float*)d_in[1];
  const float* Wrk = (const float*)d_in[2];
  const float* brk = (const float*)d_in[3];
  float* out = (float*)d_out;

  char* ws = (char*)d_ws;
  float* rk = (float*)ws;                          // 32*128*4      = 16384 B
  float* rknorm = (float*)(ws + 16384);            // 128*4         = 512 B
  float* cand_d = (float*)(ws + 16896);            // 32*4*64*8*4   = 262144 B
  int* cand_i = (int*)(ws + 16896 + 262144);       // 262144 B

  rk_kernel<<<Bb, 128, 0, stream>>>(xi, Wrk, brk, rk, rknorm);
  dim3 gridA(NB_A, Bb);
  topk_partial<<<gridA, TPB_A, 0, stream>>>(sparse, rk, rknorm, cand_d, cand_i);
  topk_final<<<Bb * Rr, 64, 0, stream>>>(sparse, cand_d, cand_i, out);
}

// Round 7
// 92.042 us; speedup vs baseline: 2.7264x; 1.4732x over previous
//
#include <hip/hip_runtime.h>

// Problem constants (from reference setup_inputs)
constexpr int Bb = 32;      // batch
constexpr int Mm = 65536;   // memory slots
constexpr int Ww = 32;      // word width
constexpr int Rr = 4;      // read heads
constexpr int Dd = 256;     // d_in
constexpr int Kk = 8;       // K_NEIGHBORS

constexpr int NB_A = 64;                    // blocks per batch, phase A
constexpr int TPB_A = 256;                  // threads per block
constexpr int ROWS_PER_BLOCK = Mm / NB_A;   // 1024
constexpr int TILE_ROWS = 128;              // rows per LDS tile (2 thr/row)
constexpr int TILES = ROWS_PER_BLOCK / TILE_ROWS;  // 8
constexpr int NBUF = 3;                     // ring buffers (prefetch dist 2)
constexpr int CPL = NB_A * Kk / 64;         // final-merge candidates/lane = 8

// async global->LDS, 16 B per lane; LDS dest = uniform base + lane*16
__device__ __forceinline__ void glds16(const float4* src, float4* dst_lds) {
  __builtin_amdgcn_global_load_lds(
      (const __attribute__((address_space(1))) void*)src,
      (__attribute__((address_space(3))) void*)dst_lds, 16, 0, 0);
}

// ---------------------------------------------------------------------------
// Kernel 1: read_keys = xi @ W_rk^T + b_rk  (32 x 128), plus ||rk||^2 per (b,r)
// ---------------------------------------------------------------------------
__global__ __launch_bounds__(128) void rk_kernel(
    const float* __restrict__ xi, const float* __restrict__ Wrk,
    const float* __restrict__ brk, float* __restrict__ rk,
    float* __restrict__ rknorm) {
  const int b = blockIdx.x;
  const int tid = threadIdx.x;  // 128 threads = one rw each
  __shared__ float xs[Dd];
  __shared__ float rks[Rr * Ww];
  #pragma unroll
  for (int i = 0; i < Dd; i += 128) xs[i + tid] = xi[b * Dd + i + tid];
  __syncthreads();
  float acc = brk[tid];
  const float4* wr = reinterpret_cast<const float4*>(Wrk + (size_t)tid * Dd);
  #pragma unroll 4
  for (int i = 0; i < Dd / 4; ++i) {
    float4 wv = wr[i];
    acc = fmaf(wv.x, xs[4 * i + 0], acc);
    acc = fmaf(wv.y, xs[4 * i + 1], acc);
    acc = fmaf(wv.z, xs[4 * i + 2], acc);
    acc = fmaf(wv.w, xs[4 * i + 3], acc);
  }
  rk[b * Rr * Ww + tid] = acc;
  rks[tid] = acc;
  __syncthreads();
  if (tid < Rr) {
    float s = 0.f;
    #pragma unroll
    for (int j = 0; j < Ww; ++j) s = fmaf(rks[tid * Ww + j], rks[tid * Ww + j], s);
    rknorm[b * Rr + tid] = s;
  }
}

// ---------------------------------------------------------------------------
// Kernel 2: ring-3 gload_lds pipeline (prefetch distance 2, counted vmcnt,
// no barriers in the streaming loop - wave-private staging/reads). 128-row
// tiles, 2 threads/row, one shfl_xor(1) finishes each distance. Chunk
// XOR-swizzle: pre-swizzled GLOBAL source + swizzled LDS READ. Extraction:
// even threads (each owns local row tid/2) dump d8 to LDS; wave w then
// extracts ONLY head w's block top-8 (8 rounds, 96 shfl/wave total).
// ---------------------------------------------------------------------------
__global__ __launch_bounds__(TPB_A, 2) void topk_partial(
    const float* __restrict__ sparse, const float* __restrict__ rk,
    const float* __restrict__ rknorm, float* __restrict__ cand_d,
    int* __restrict__ cand_i) {
  const int b = blockIdx.y;
  const int tid = threadIdx.x;
  const int lane = tid & 63;
  const int wid = tid >> 6;
  const float INF = __builtin_inff();

  __shared__ float4 rk4[Rr][8];               // 512 B
  __shared__ float rkn_s[Rr];
  __shared__ float4 tile[NBUF][TILE_ROWS * 8];  // 3 x 16 KB

  if (tid < Rr * Ww) reinterpret_cast<float*>(rk4)[tid] = rk[b * Rr * Ww + tid];
  if (tid < Rr) rkn_s[tid] = rknorm[b * Rr + tid];
  __syncthreads();

  float rkn[Rr];
  #pragma unroll
  for (int r = 0; r < Rr; ++r) rkn[r] = rkn_s[r];

  const int rowBlk = blockIdx.x * ROWS_PER_BLOCK;
  const float4* sb4 =
      reinterpret_cast<const float4*>(sparse) + (size_t)b * Mm * 8;
  // staging source permutation: LDS slot (row, s) receives global chunk
  // s ^ (row&7); groups are 8-row aligned so row&7 == lane>>3 within a gload
  const int perm = ((lane >> 3) * 8) + ((lane & 7) ^ (lane >> 3));

  const int rowL = wid * 32 + (lane >> 1);  // local tile row (2 thr/row)
  const int rmask = rowL & 7;
  const int hsel = (tid & 1) * 4;           // this thread's 4 chunks

  float d8[Rr][TILES];

  // wave wid stages rows [wid*32, wid*32+32) of a tile: 4 x 1 KB gload_lds
  auto STAGE = [&](int buf, int t) {
    const float4* g0 = sb4 + (size_t)(rowBlk + t * TILE_ROWS + wid * 32) * 8;
    float4* l0 = &tile[buf][wid * 32 * 8];
    #pragma unroll
    for (int i = 0; i < 4; ++i) glds16(g0 + i * 64 + perm, l0 + i * 64);
  };

  STAGE(0, 0);
  STAGE(1, 1);
  #pragma unroll
  for (int t = 0; t < TILES; ++t) {
    if (t + 2 < TILES) {
      // this wave's reads of buf (t+2)%3 (== tile t-1) are done (WAR)
      asm volatile("s_waitcnt lgkmcnt(0)" ::: "memory");
      STAGE((t + 2) % NBUF, t + 2);
      asm volatile("s_waitcnt vmcnt(8)" ::: "memory");  // tile t landed
    } else if (t + 1 < TILES) {
      asm volatile("s_waitcnt vmcnt(4)" ::: "memory");  // tile t landed
    } else {
      asm volatile("s_waitcnt vmcnt(0)" ::: "memory");
    }
    const float4* tb = &tile[t % NBUF][rowL * 8];
    float a0 = 0.f, a1 = 0.f, a2 = 0.f, a3 = 0.f, ss = 0.f;
    #pragma unroll
    for (int j = 0; j < 4; ++j) {
      float4 v = tb[(hsel + j) ^ rmask];
      float4 k0 = rk4[0][hsel + j];
      float4 k1 = rk4[1][hsel + j];
      float4 k2 = rk4[2][hsel + j];
      float4 k3 = rk4[3][hsel + j];
      a0 = fmaf(k0.x, v.x, a0); a0 = fmaf(k0.y, v.y, a0);
      a0 = fmaf(k0.z, v.z, a0); a0 = fmaf(k0.w, v.w, a0);
      a1 = fmaf(k1.x, v.x, a1); a1 = fmaf(k1.y, v.y, a1);
      a1 = fmaf(k1.z, v.z, a1); a1 = fmaf(k1.w, v.w, a1);
      a2 = fmaf(k2.x, v.x, a2); a2 = fmaf(k2.y, v.y, a2);
      a2 = fmaf(k2.z, v.z, a2); a2 = fmaf(k2.w, v.w, a2);
      a3 = fmaf(k3.x, v.x, a3); a3 = fmaf(k3.y, v.y, a3);
      a3 = fmaf(k3.z, v.z, a3); a3 = fmaf(k3.w, v.w, a3);
      ss = fmaf(v.x, v.x, ss); ss = fmaf(v.y, v.y, ss);
      ss = fmaf(v.z, v.z, ss); ss = fmaf(v.w, v.w, ss);
    }
    // partial d2 per head = ss - 2*dot over this half; partner adds the rest
    float p0 = fmaf(-2.f, a0, ss);
    float p1 = fmaf(-2.f, a1, ss);
    float p2 = fmaf(-2.f, a2, ss);
    float p3 = fmaf(-2.f, a3, ss);
    p0 += __shfl_xor(p0, 1);
    p1 += __shfl_xor(p1, 1);
    p2 += __shfl_xor(p2, 1);
    p3 += __shfl_xor(p3, 1);
    d8[0][t] = p0 + rkn[0];
    d8[1][t] = p1 + rkn[1];
    d8[2][t] = p2 + rkn[2];
    d8[3][t] = p3 + rkn[3];
  }

  // --- extraction: dedup (even threads only; local row == tid/2), dump to
  //     LDS (reuses tile buf 0), then wave w extracts head r=w ---
  __syncthreads();  // all waves done streaming (tile bufs free)
  float* dmp = reinterpret_cast<float*>(&tile[0][0]);  // [4][128][8] = 16 KB
  if ((tid & 1) == 0) {
    const int e = tid >> 1;  // == this thread's local row
    #pragma unroll
    for (int r = 0; r < Rr; ++r) {
      float4* p = reinterpret_cast<float4*>(&dmp[(r * 128 + e) * 8]);
      p[0] = make_float4(d8[r][0], d8[r][1], d8[r][2], d8[r][3]);
      p[1] = make_float4(d8[r][4], d8[r][5], d8[r][6], d8[r][7]);
    }
  }
  __syncthreads();

  {
    const int r = wid;          // wave w handles head w
    const int e0 = 2 * lane;    // this lane's two local rows
    float v[2][8];
    #pragma unroll
    for (int q = 0; q < 2; ++q) {
      const float4* p =
          reinterpret_cast<const float4*>(&dmp[(r * 128 + e0 + q) * 8]);
      float4 lo = p[0], hi = p[1];
      v[q][0] = lo.x; v[q][1] = lo.y; v[q][2] = lo.z; v[q][3] = lo.w;
      v[q][4] = hi.x; v[q][5] = hi.y; v[q][6] = hi.z; v[q][7] = hi.w;
    }
    const int base = rowBlk + e0;  // row = base + q + s*TILE_ROWS
    size_t o = ((size_t)(b * Rr + r) * NB_A + blockIdx.x) * Kk;
    #pragma unroll
    for (int k = 0; k < Kk; ++k) {
      // per-lane argmin over 16 static slots with global-row tie-break
      float lv = v[0][0];
      int lrow = base;
      #pragma unroll
      for (int q = 0; q < 2; ++q)
        #pragma unroll
        for (int s = 0; s < 8; ++s) {
          if (q == 0 && s == 0) continue;
          int row = base + q + s * TILE_ROWS;
          if (v[q][s] < lv || (v[q][s] == lv && row < lrow)) {
            lv = v[q][s]; lrow = row;
          }
        }
      // wave butterfly argmin
      float bv = lv;
      int bi = lrow;
      #pragma unroll
      for (int off = 32; off; off >>= 1) {
        float ov = __shfl_xor(bv, off);
        int oi = __shfl_xor(bi, off);
        if (ov < bv || (ov == bv && oi < bi)) { bv = ov; bi = oi; }
      }
      if (lane == 0) { cand_d[o + k] = bv; cand_i[o + k] = bi; }
      // winner slot (value AND row match) -> INF; static indexing
      #pragma unroll
      for (int q = 0; q < 2; ++q)
        #pragma unroll
        for (int s = 0; s < 8; ++s) {
          bool clr = (v[q][s] == bv) && (base + q + s * TILE_ROWS == bi);
          v[q][s] = clr ? INF : v[q][s];
        }
    }
  }
}

// ---------------------------------------------------------------------------
// Kernel 3: merge 64*8 candidates per (b,r) -> global top-8, weights, gather
// ---------------------------------------------------------------------------
__global__ __launch_bounds__(64) void topk_final(
    const float* __restrict__ sparse, const float* __restrict__ cand_d,
    const int* __restrict__ cand_i, float* __restrict__ out) {
  const int br = blockIdx.x;  // b*4 + r
  const int b = br >> 2;
  const int r = br & 3;
  const int lane = threadIdx.x;  // 64
  const float INF = __builtin_inff();

  float ld[CPL];
  int li[CPL];
  const float* cd = cand_d + (size_t)br * (NB_A * Kk);
  const int* ci = cand_i + (size_t)br * (NB_A * Kk);
  #pragma unroll
  for (int t = 0; t < CPL; ++t) {
    ld[t] = cd[t * 64 + lane];
    li[t] = ci[t * 64 + lane];
  }
  // sort per-lane list ascending (static bubble network)
  #pragma unroll
  for (int i = 0; i < CPL - 1; ++i)
    #pragma unroll
    for (int j = 0; j < CPL - 1 - i; ++j)
      if (ld[j + 1] < ld[j] || (ld[j + 1] == ld[j] && li[j + 1] < li[j])) {
        float td = ld[j]; ld[j] = ld[j + 1]; ld[j + 1] = td;
        int ti = li[j]; li[j] = li[j + 1]; li[j + 1] = ti;
      }

  __shared__ float s_td[Kk];
  __shared__ int s_ti[Kk];
  #pragma unroll
  for (int k = 0; k < Kk; ++k) {
    float v = ld[0];
    int id = li[0];
    #pragma unroll
    for (int off = 32; off; off >>= 1) {  // butterfly: all lanes get the min
      float ov = __shfl_xor(v, off);
      int oi = __shfl_xor(id, off);
      if (ov < v || (ov == v && oi < id)) { v = ov; id = oi; }
    }
    if (lane == 0) { s_td[k] = v; s_ti[k] = id; }
    if (li[0] == id) {  // owner pops head
      #pragma unroll
      for (int j = 0; j < CPL - 1; ++j) { ld[j] = ld[j + 1]; li[j] = li[j + 1]; }
      ld[CPL - 1] = INF;
      li[CPL - 1] = -1;
    }
  }
  __syncthreads();

  // read_weights[r][b][k] = dist_k / dist_7  (dist ascending -> max is last)
  const float dmax = s_td[Kk - 1];
  if (lane < Kk)
    out[(size_t)Rr * Bb * Kk * Ww + ((size_t)r * Bb + b) * Kk + lane] =
        s_td[lane] / dmax;

  // read_vectors[r][b][k][j] = sparse[b][idx_k][j]
  const float* sbase = sparse + (size_t)b * Mm * Ww;
  #pragma unroll
  for (int t = 0; t < (Kk * Ww) / 64; ++t) {
    int e = t * 64 + lane;
    int k = e >> 5;
    int j = e & 31;
    out[(((size_t)r * Bb + b) * Kk + k) * Ww + j] =
        sbase[(size_t)s_ti[k] * Ww + j];
  }
}

// ---------------------------------------------------------------------------
extern "C" void kernel_launch(void* const* d_in, const int* in_sizes, int n_in,
                              void* d_out, int out_size, void* d_ws,
                              size_t ws_size, hipStream_t stream) {
  const float* xi = (const float*)d_in[0];
  const float* sparse = (const float*)d_in[1];
  const float* Wrk = (const float*)d_in[2];
  const float* brk = (const float*)d_in[3];
  float* out = (float*)d_out;

  char* ws = (char*)d_ws;
  float* rk = (float*)ws;                          // 32*128*4      = 16384 B
  float* rknorm = (float*)(ws + 16384);            // 128*4         = 512 B
  float* cand_d = (float*)(ws + 16896);            // 32*4*64*8*4   = 262144 B
  int* cand_i = (int*)(ws + 16896 + 262144);       // 262144 B

  rk_kernel<<<Bb, 128, 0, stream>>>(xi, Wrk, brk, rk, rknorm);
  dim3 gridA(NB_A, Bb);
  topk_partial<<<gridA, TPB_A, 0, stream>>>(sparse, rk, rknorm, cand_d, cand_i);
  topk_final<<<Bb * Rr, 64, 0, stream>>>(sparse, cand_d, cand_i, out);
}